// Round 5
// baseline (758.778 us; speedup 1.0000x reference)
//
#include <hip/hip_runtime.h>

// ---------------- problem constants ----------------
#define NCELLS 131072
#define HIDN 256
#define ODIM 128
#define FS 16384
#define DCC 4096
#define HALF_NOISE 16777216u   // (NCELLS*HIDN)/2

// ---------------- ws layout (bytes) ----------------
#define WS_WAG   0u          // 256x256 bf16 (a/g layer-1 h-part), [ch][k]
#define WS_W2C   131072u     // 128x256 bf16 ([a_w2 | -g_w2]), [ch][k]
#define WS_WIH   196608u     // 768x128 bf16 (gru_wih[:, :128]), [ch][k]
#define WS_WHH   393216u     // 768x256 bf16 (gru_whh), [ch][k]
#define WS_BAG   786432u     // 256 f32 folded layer-1 bias
#define WS_B2C   787456u     // 128 f32 (a_b2 - g_b2)
#define WS_ACC   788480u     // f32: fsum[2048] fsumdc[2048] combined[128] sumexp sumt
#define ACC_F     (WS_ACC/4)
#define ACC_BYTES 17152u
#define WS_FM    805632u     // 2048 f32
#define WS_GOP   813824u     // 256 f32
#define WS_GMEAN 814848u     // 256 f32

typedef __bf16 bf16x8 __attribute__((ext_vector_type(8)));
typedef float floatx4 __attribute__((ext_vector_type(4)));
#define MFMA16(a,b,c) __builtin_amdgcn_mfma_f32_16x16x32_bf16((a),(b),(c),0,0,0)

__device__ __forceinline__ unsigned short f2bf(float f){
  union { float f; unsigned int u; } v; v.f = f;
  unsigned int u = v.u;
  unsigned int r = (u + 0x7FFFu + ((u >> 16) & 1u)) >> 16;
  return (unsigned short)r;
}
__device__ __forceinline__ float bf2f(unsigned short s){
  union { unsigned int u; float f; } v; v.u = ((unsigned int)s) << 16; return v.f;
}
__device__ __forceinline__ float sigm(float x){ return 1.0f/(1.0f + expf(-x)); }

// swizzled LDS fragment load: element offset = row*width + (chunk ^ (row&7))*8
__device__ __forceinline__ bf16x8 ldfrag(const unsigned short* base, int row, int chunk, int width){
  return *(const bf16x8*)(base + row*width + (((chunk ^ (row & 7))) << 3));
}

// ---------------- threefry2x32, key = (0, 42) ----------------
__device__ __forceinline__ unsigned int rotl32(unsigned int x, int r){ return (x<<r)|(x>>(32-r)); }
__device__ __forceinline__ void threefry_0_42(unsigned int x0, unsigned int x1,
                                              unsigned int& o0, unsigned int& o1){
  const unsigned int k0 = 0u, k1 = 42u, k2 = 0x1BD11BDAu ^ 0u ^ 42u;
  x0 += k0; x1 += k1;
#define TFR(r) { x0 += x1; x1 = rotl32(x1,(r)); x1 ^= x0; }
  TFR(13) TFR(15) TFR(26) TFR(6)
  x0 += k1; x1 += k2 + 1u;
  TFR(17) TFR(29) TFR(16) TFR(24)
  x0 += k2; x1 += k0 + 2u;
  TFR(13) TFR(15) TFR(26) TFR(6)
  x0 += k0; x1 += k1 + 3u;
  TFR(17) TFR(29) TFR(16) TFR(24)
  x0 += k1; x1 += k2 + 4u;
  TFR(13) TFR(15) TFR(26) TFR(6)
  x0 += k2; x1 += k0 + 5u;
#undef TFR
  o0 = x0; o1 = x1;
}

// JAX partitionable-mode 32-bit random bits: full cipher of (idx>>32, idx) -> x0^x1
__device__ __forceinline__ unsigned int tf_bits_partitionable(unsigned int idx){
  unsigned int o0, o1;
  threefry_0_42(0u, idx, o0, o1);
  return o0 ^ o1;
}

__device__ __forceinline__ float giles_erfinv(float x){
  float w = -log1pf(-x*x);          // matches XLA ErfInv f32
  float p;
  if (w < 5.0f){
    w = w - 2.5f;
    p = 2.81022636e-08f;
    p = 3.43273939e-07f + p*w;
    p = -3.5233877e-06f + p*w;
    p = -4.39150654e-06f + p*w;
    p = 0.00021858087f  + p*w;
    p = -0.00125372503f + p*w;
    p = -0.00417768164f + p*w;
    p = 0.246640727f    + p*w;
    p = 1.50140941f     + p*w;
  } else {
    w = sqrtf(w) - 3.0f;
    p = -0.000200214257f;
    p = 0.000100950558f + p*w;
    p = 0.00134934322f  + p*w;
    p = -0.00367342844f + p*w;
    p = 0.00573950773f  + p*w;
    p = -0.0076224613f  + p*w;
    p = 0.00943887047f  + p*w;
    p = 1.00167406f     + p*w;
    p = 2.83297682f     + p*w;
  }
  return p*x;
}
__device__ __forceinline__ float bits_to_normal(unsigned int bits){
  union { unsigned int u; float f; } v; v.u = (bits >> 9) | 0x3f800000u;
  float f = v.f - 1.0f;                       // [0,1)
  const float lo = -0.99999994f;              // nextafter(-1,0)
  float u = fmaf(f, 2.0f, lo);                // matches jax uniform(lo, 1.0)
  u = fmaxf(u, lo);
  return 1.41421356237f * giles_erfinv(u);
}

// ---------------- prep: weight bf16 conversion ----------------
__global__ void k_prep_w(const float* a_w1, const float* g_w1, const float* a_w2, const float* g_w2,
                         const float* gru_wih, const float* gru_whh, unsigned short* ws16){
  int i = blockIdx.x*256 + threadIdx.x;
  if (i < 65536){                    // Wag
    int ch = i >> 8, k = i & 255;
    float v = (ch < 128) ? a_w1[ch*384 + 128 + k] : g_w1[(ch-128)*384 + 128 + k];
    ws16[WS_WAG/2 + i] = f2bf(v);
  } else if (i < 98304){             // W2c
    int j = i - 65536; int ch = j >> 8, k = j & 255;
    float v = (k < 128) ? a_w2[ch*128 + k] : -g_w2[ch*128 + (k-128)];
    ws16[WS_W2C/2 + j] = f2bf(v);
  } else if (i < 196608){            // Wih (k<128 part)
    int j = i - 98304; int ch = j >> 7, k = j & 127;
    ws16[WS_WIH/2 + j] = f2bf(gru_wih[ch*129 + k]);
  } else if (i < 393216){            // Whh
    int j = i - 196608; int ch = j >> 8, k = j & 255;
    ws16[WS_WHH/2 + j] = f2bf(gru_whh[ch*256 + k]);
  }
}

// fold x into layer-1 bias; combine layer-2 bias
__global__ void k_prep_b(const float* x, const float* a_w1, const float* g_w1,
                         const float* a_b1, const float* g_b1,
                         const float* a_b2, const float* g_b2, float* wsf){
  int t = threadIdx.x;  // 256
  const float* wr = (t < 128) ? (a_w1 + t*384) : (g_w1 + (t-128)*384);
  float b = (t < 128) ? a_b1[t] : g_b1[t-128];
  float s = 0.f;
  for (int k = 0; k < 128; ++k) s += x[k]*wr[k];
  wsf[WS_BAG/4 + t] = b + s;
  if (t < 128) wsf[WS_B2C/4 + t] = a_b2[t] - g_b2[t];
}

// ---------------- D-stage GEMM helpers (wave tile 64 rows x 32 ch) ----------------
__device__ __forceinline__ void gemm_gi(floatx4 acc[4][2], const unsigned short* Wih,
                                        const unsigned short* outlds, int cb, int lane, int rowoff){
  const int al = lane & 15, kg = lane >> 4;
#pragma unroll
  for (int kk = 0; kk < 4; ++kk){
    const int chunk = kk*4 + kg;
    bf16x8 a0 = ldfrag(outlds,      al, chunk, 128);
    bf16x8 a1 = ldfrag(outlds, 16 + al, chunk, 128);
    bf16x8 a2 = ldfrag(outlds, 32 + al, chunk, 128);
    bf16x8 a3 = ldfrag(outlds, 48 + al, chunk, 128);
    const int k = kk*32 + kg*8;
    bf16x8 b0 = *(const bf16x8*)(Wih + (rowoff + cb      + al)*128 + k);
    bf16x8 b1 = *(const bf16x8*)(Wih + (rowoff + cb + 16 + al)*128 + k);
    acc[0][0] = MFMA16(a0,b0,acc[0][0]); acc[1][0] = MFMA16(a1,b0,acc[1][0]);
    acc[2][0] = MFMA16(a2,b0,acc[2][0]); acc[3][0] = MFMA16(a3,b0,acc[3][0]);
    acc[0][1] = MFMA16(a0,b1,acc[0][1]); acc[1][1] = MFMA16(a1,b1,acc[1][1]);
    acc[2][1] = MFMA16(a2,b1,acc[2][1]); acc[3][1] = MFMA16(a3,b1,acc[3][1]);
  }
}
__device__ __forceinline__ void gemm_gh(floatx4 acc[4][2], const unsigned short* Whh,
                                        const unsigned short* hlds, int cb, int lane, int rowoff){
  const int al = lane & 15, kg = lane >> 4;
#pragma unroll
  for (int kk = 0; kk < 8; ++kk){
    const int chunk = kk*4 + kg;
    bf16x8 a0 = ldfrag(hlds,      al, chunk, 256);
    bf16x8 a1 = ldfrag(hlds, 16 + al, chunk, 256);
    bf16x8 a2 = ldfrag(hlds, 32 + al, chunk, 256);
    bf16x8 a3 = ldfrag(hlds, 48 + al, chunk, 256);
    const int k = kk*32 + kg*8;
    bf16x8 b0 = *(const bf16x8*)(Whh + (rowoff + cb      + al)*256 + k);
    bf16x8 b1 = *(const bf16x8*)(Whh + (rowoff + cb + 16 + al)*256 + k);
    acc[0][0] = MFMA16(a0,b0,acc[0][0]); acc[1][0] = MFMA16(a1,b0,acc[1][0]);
    acc[2][0] = MFMA16(a2,b0,acc[2][0]); acc[3][0] = MFMA16(a3,b0,acc[3][0]);
    acc[0][1] = MFMA16(a0,b1,acc[0][1]); acc[1][1] = MFMA16(a1,b1,acc[1][1]);
    acc[2][1] = MFMA16(a2,b1,acc[2][1]); acc[3][1] = MFMA16(a3,b1,acc[3][1]);
  }
}

// ---------------- pass 1: per-cell pipeline, 64 rows/block, 512 thr ----------------
__global__ __launch_bounds__(512, 2) void k_pass1(
    const float* __restrict__ hiddens, const float* __restrict__ payoffs,
    const float* __restrict__ gru_wih, const float* __restrict__ gru_bih,
    const float* __restrict__ gru_bhh,
    const unsigned short* __restrict__ ws16, const float* __restrict__ wsf,
    float* __restrict__ accf, float* __restrict__ d_out)
{
  __shared__ __align__(16) unsigned short h_lds[64*256];  // 32 KB
  __shared__ __align__(16) unsigned short u1[64*256];     // 32 KB: r1 -> out + scalars
  unsigned short* u2 = u1;                 // out 64x128 (first 8192 ushorts)
  float* tens = (float*)&u1[8192];         // 64 f32
  float* texp = tens + 64;                 // 64 f32
  float* pay  = tens + 128;                // 64 f32
  float* bsum = tens + 192;                // 256 f32

  const int tid = threadIdx.x;
  const int lane = tid & 63;
  const int wid  = tid >> 6;
  const int row0 = blockIdx.x * 64;
  const int al = lane & 15, kg = lane >> 4;
  const floatx4 vzero = {0.f, 0.f, 0.f, 0.f};

  // ---- stage h -> LDS (bf16, swizzled) ----
  {
    const float4* hg = (const float4*)(hiddens + (size_t)row0*256);
#pragma unroll
    for (int it = 0; it < 8; ++it){
      int i = it*512 + tid;            // 4096 float4 per tile
      float4 v = hg[i];
      int row = i >> 6;
      int ch  = (i & 63) << 2;
      int off = row*256 + (((ch >> 3) ^ (row & 7)) << 3) + (ch & 7);
      h_lds[off+0] = f2bf(v.x); h_lds[off+1] = f2bf(v.y);
      h_lds[off+2] = f2bf(v.z); h_lds[off+3] = f2bf(v.w);
    }
  }
  __syncthreads();

  // ---- stage A: [a1|g1] = relu(h @ Wag^T + bag) -> u1 ----
  {
    const unsigned short* Wag = ws16 + WS_WAG/2;
    const int mrow = (wid >> 2) * 32;
    const int ncol = (wid & 3) * 64;
    floatx4 acc[2][4];
#pragma unroll
    for (int m=0;m<2;m++)
#pragma unroll
      for (int n=0;n<4;n++) acc[m][n] = vzero;
#pragma unroll
    for (int kk = 0; kk < 8; ++kk){
      const int chunk = kk*4 + kg;
      bf16x8 a0 = ldfrag(h_lds, mrow      + al, chunk, 256);
      bf16x8 a1 = ldfrag(h_lds, mrow + 16 + al, chunk, 256);
      const int k = kk*32 + kg*8;
      bf16x8 b0 = *(const bf16x8*)(Wag + (ncol      + al)*256 + k);
      bf16x8 b1 = *(const bf16x8*)(Wag + (ncol + 16 + al)*256 + k);
      bf16x8 b2 = *(const bf16x8*)(Wag + (ncol + 32 + al)*256 + k);
      bf16x8 b3 = *(const bf16x8*)(Wag + (ncol + 48 + al)*256 + k);
      acc[0][0] = MFMA16(a0,b0,acc[0][0]); acc[1][0] = MFMA16(a1,b0,acc[1][0]);
      acc[0][1] = MFMA16(a0,b1,acc[0][1]); acc[1][1] = MFMA16(a1,b1,acc[1][1]);
      acc[0][2] = MFMA16(a0,b2,acc[0][2]); acc[1][2] = MFMA16(a1,b2,acc[1][2]);
      acc[0][3] = MFMA16(a0,b3,acc[0][3]); acc[1][3] = MFMA16(a1,b3,acc[1][3]);
    }
#pragma unroll
    for (int n=0;n<4;n++){
      int ch = ncol + n*16 + al;
      float bias = wsf[WS_BAG/4 + ch];
#pragma unroll
      for (int m=0;m<2;m++){
#pragma unroll
        for (int r=0;r<4;r++){
          int row = mrow + m*16 + kg*4 + r;
          float val = fmaxf(acc[m][n][r] + bias, 0.f);
          u1[row*256 + (((ch>>3) ^ (row&7))<<3) + (ch&7)] = f2bf(val);
        }
      }
    }
  }
  __syncthreads();

  // ---- stage B: out = r1 @ W2c^T + b2c (keep in regs across barrier) ----
  floatx4 bacc[2][2];
  const int bmrow = (wid >> 2) * 32;
  const int bncol = (wid & 3) * 32;
  {
    const unsigned short* W2c = ws16 + WS_W2C/2;
#pragma unroll
    for (int m=0;m<2;m++)
#pragma unroll
      for (int n=0;n<2;n++) bacc[m][n] = vzero;
#pragma unroll
    for (int kk = 0; kk < 8; ++kk){
      const int chunk = kk*4 + kg;
      bf16x8 a0 = ldfrag(u1, bmrow      + al, chunk, 256);
      bf16x8 a1 = ldfrag(u1, bmrow + 16 + al, chunk, 256);
      const int k = kk*32 + kg*8;
      bf16x8 b0 = *(const bf16x8*)(W2c + (bncol      + al)*256 + k);
      bf16x8 b1 = *(const bf16x8*)(W2c + (bncol + 16 + al)*256 + k);
      bacc[0][0] = MFMA16(a0,b0,bacc[0][0]); bacc[1][0] = MFMA16(a1,b0,bacc[1][0]);
      bacc[0][1] = MFMA16(a0,b1,bacc[0][1]); bacc[1][1] = MFMA16(a1,b1,bacc[1][1]);
    }
  }
  __syncthreads();   // everyone done reading r1 -> reuse u1 for out
  {
#pragma unroll
    for (int n=0;n<2;n++){
      int ch = bncol + n*16 + al;
      float bias = wsf[WS_B2C/4 + ch];
#pragma unroll
      for (int m=0;m<2;m++){
#pragma unroll
        for (int r=0;r<4;r++){
          int row = bmrow + m*16 + kg*4 + r;
          u2[row*128 + (((ch>>3) ^ (row&7))<<3) + (ch&7)] = f2bf(bacc[m][n][r] + bias);
        }
      }
    }
  }
  __syncthreads();

  // ---- tension ----
  if (tid < 256){
    int row = tid >> 2, part = tid & 3;
    float s = 0.f;
    for (int c = 0; c < 32; ++c){
      int ch = part*32 + c;
      float o = bf2f(u2[row*128 + (((ch>>3) ^ (row&7))<<3) + (ch&7)]);
      s += o*o;
    }
    bsum[tid] = s;
  }
  __syncthreads();
  if (tid < 64){
    float t = (bsum[tid*4] + bsum[tid*4+1] + bsum[tid*4+2] + bsum[tid*4+3]) * (1.0f/128.0f);
    tens[tid] = t;
    texp[tid] = expf(t);
    pay[tid]  = payoffs[row0 + tid];
  }
  __syncthreads();

  // ---- softmax-mixture partials (waves 0-2 only; no hazard with D stages) ----
  if (tid < 128){
    int ch = tid;
    float s = 0.f;
    for (int row = 0; row < 64; ++row)
      s += texp[row] * bf2f(u2[row*128 + (((ch>>3) ^ (row&7))<<3) + (ch&7)]);
    atomicAdd(accf + ACC_F + 4096 + ch, s);
  } else if (tid == 128){
    float se = 0.f, st = 0.f;
    for (int r = 0; r < 64; ++r){ se += texp[r]; st += tens[r]; }
    atomicAdd(accf + ACC_F + 4224, se);
    atomicAdd(accf + ACC_F + 4225, st);
  }

  // ---- GRU: wave handles 64 rows x 32 channels (cb = wid*32) ----
  const unsigned short* Wih = ws16 + WS_WIH/2;
  const unsigned short* Whh = ws16 + WS_WHH/2;
  const int cb = wid * 32;

  float rr[4][2][4];
  {
    floatx4 acc[4][2];
#pragma unroll
    for (int m=0;m<4;m++){ acc[m][0] = vzero; acc[m][1] = vzero; }
    gemm_gi(acc, Wih, u2, cb, lane, 0);
    gemm_gh(acc, Whh, h_lds, cb, lane, 0);
#pragma unroll
    for (int n=0;n<2;n++){
      int ch = cb + n*16 + al;
      float bb = gru_bih[ch] + gru_bhh[ch];
      float wt = gru_wih[ch*129 + 128];
#pragma unroll
      for (int m=0;m<4;m++)
#pragma unroll
        for (int r=0;r<4;r++){
          int row = m*16 + kg*4 + r;
          rr[m][n][r] = sigm(acc[m][n][r] + bb + tens[row]*wt);
        }
    }
  }

  float nnv[4][2][4];
  {
    floatx4 gin[4][2], ghn[4][2];
#pragma unroll
    for (int m=0;m<4;m++){ gin[m][0]=vzero; gin[m][1]=vzero; ghn[m][0]=vzero; ghn[m][1]=vzero; }
    gemm_gi(gin, Wih, u2, cb, lane, 512);
    gemm_gh(ghn, Whh, h_lds, cb, lane, 512);
#pragma unroll
    for (int n=0;n<2;n++){
      int ch = cb + n*16 + al;
      float bi = gru_bih[512+ch];
      float bh = gru_bhh[512+ch];
      float wt = gru_wih[(512+ch)*129 + 128];
#pragma unroll
      for (int m=0;m<4;m++)
#pragma unroll
        for (int r=0;r<4;r++){
          int row = m*16 + kg*4 + r;
          nnv[m][n][r] = tanhf(gin[m][n][r] + bi + tens[row]*wt + rr[m][n][r]*(ghn[m][n][r] + bh));
        }
    }
  }

  {
    floatx4 acc[4][2];
#pragma unroll
    for (int m=0;m<4;m++){ acc[m][0] = vzero; acc[m][1] = vzero; }
    gemm_gi(acc, Wih, u2, cb, lane, 256);
    gemm_gh(acc, Whh, h_lds, cb, lane, 256);
    float cs[2] = {0.f, 0.f};
#pragma unroll
    for (int n=0;n<2;n++){
      int ch = cb + n*16 + al;
      float bb = gru_bih[256+ch] + gru_bhh[256+ch];
      float wt = gru_wih[(256+ch)*129 + 128];
#pragma unroll
      for (int m=0;m<4;m++)
#pragma unroll
        for (int r=0;r<4;r++){
          int row = m*16 + kg*4 + r;
          float z = sigm(acc[m][n][r] + bb + tens[row]*wt);
          float h = bf2f(h_lds[row*256 + (((ch>>3) ^ (row&7))<<3) + (ch&7)]);
          float nh = (1.0f - z)*nnv[m][n][r] + z*h;
          nh *= (0.9f + 0.02f*pay[row]);
          nh = fminf(fmaxf(nh, -10.0f), 10.0f);
          d_out[129 + (size_t)(row0 + row)*256 + ch] = nh;
          cs[n] += nh;
        }
    }
#pragma unroll
    for (int n=0;n<2;n++){
      float c = cs[n];
      c += __shfl_xor(c, 16);
      c += __shfl_xor(c, 32);
      if (lane < 16) bsum[cb + n*16 + lane] = c;
    }
  }
  __syncthreads();

  if (tid < 256){
    int f = row0 >> 14;
    atomicAdd(accf + ACC_F + f*256 + tid, bsum[tid]);
    if ((row0 & (FS-1)) < DCC)
      atomicAdd(accf + ACC_F + 2048 + f*256 + tid, bsum[tid]);
  }
}

// ---------------- mid: faction stats + head ----------------
__global__ void k_mid(const float* __restrict__ accf, float* __restrict__ wsf,
                      const float* __restrict__ head_w, const float* __restrict__ head_b,
                      const int* __restrict__ stepp, float* __restrict__ d_out){
  int t = threadIdx.x;  // 256
  const float* fsum   = accf + ACC_F;
  const float* fsumdc = fsum + 2048;
  const float* comb   = fsum + 4096;
  int step = *stepp;

  float g = 0.f;
  for (int f = 0; f < 8; ++f) g += fsum[f*256 + t];
  float gop = g * (1.0f/131072.0f);
  wsf[WS_GOP/4 + t] = gop;

  float tot = 0.f;
  for (int f = 0; f < 8; ++f){
    float s1  = fsum[f*256 + t];
    float fmv = s1 * (1.0f/16384.0f);
    wsf[WS_FM/4 + f*256 + t] = fmv;
    float sh2 = s1;
    if (step > 5){
      float sdc = 0.85f*fsumdc[f*256 + t] + 0.15f*4096.0f*fmv;
      sh2 = s1 + 0.15f*(4096.0f*gop - sdc);
    }
    tot += sh2;
  }
  wsf[WS_GMEAN/4 + t] = tot * (1.0f/131072.0f);

  if (t < 128){
    float inv = 1.0f / fsum[4224];
    float p = head_b[t];
    for (int ch = 0; ch < 128; ++ch) p += head_w[t*128 + ch] * (comb[ch]*inv);
    d_out[t] = p;
  }
  if (t == 0) d_out[128] = fsum[4225] * (1.0f/131072.0f);
}

// ---------------- pass 2: sync/debate/coop/noise, in place in d_out ----------------
__global__ __launch_bounds__(256) void k_pass2(float* __restrict__ dout,
                                               const int* __restrict__ last_action,
                                               const float* __restrict__ wsf,
                                               const int* __restrict__ stepp){
  const int t = threadIdx.x;
  const int rA = blockIdx.x*8 + (t >> 5);
  const int rB = rA + 65536;
  const int ch0 = (t & 31) * 8;
  const int step = *stepp;
  const float* fm    = wsf + WS_FM/4;
  const float* gop   = wsf + WS_GOP/4;
  const float* gmean = wsf + WS_GMEAN/4;
  const int coopA = last_action[rA];
  const int coopB = last_action[rB];
  const bool debA = (step > 5) && ((rA & (FS-1)) < DCC);
  const bool debB = (step > 5) && ((rB & (FS-1)) < DCC);
  const int fA = rA >> 14, fB = rB >> 14;
  float* pa = dout + 129 + (size_t)rA*256 + ch0;
  float* pb = dout + 129 + (size_t)rB*256 + ch0;

  float va[8], vb[8];
#pragma unroll
  for (int i=0;i<8;i++){ va[i] = pa[i]; vb[i] = pb[i]; }
#pragma unroll
  for (int i=0;i<8;i++){
    int ch = ch0 + i;
    float p = 0.85f*va[i] + 0.15f*fm[fA*256 + ch];
    if (debA) p = 0.85f*p + 0.15f*gop[ch];
    if (coopA) p += 0.05f*(gmean[ch] - p);
    va[i] = p;
    float q = 0.85f*vb[i] + 0.15f*fm[fB*256 + ch];
    if (debB) q = 0.85f*q + 0.15f*gop[ch];
    if (coopB) q += 0.05f*(gmean[ch] - q);
    vb[i] = q;
  }
  // JAX partitionable threefry noise: bits(idx) = x0^x1 of cipher(0, idx)
  if (!coopA){
    const unsigned baseA = (unsigned)rA*256u + (unsigned)ch0;
#pragma unroll
    for (int i=0;i<8;i++)
      va[i] += 0.02f*bits_to_normal(tf_bits_partitionable(baseA + i));
  }
  if (!coopB){
    const unsigned baseB = (unsigned)rA*256u + (unsigned)ch0 + HALF_NOISE;
#pragma unroll
    for (int i=0;i<8;i++)
      vb[i] += 0.02f*bits_to_normal(tf_bits_partitionable(baseB + i));
  }
#pragma unroll
  for (int i=0;i<8;i++){
    pa[i] = fminf(fmaxf(va[i], -10.f), 10.f);
    pb[i] = fminf(fmaxf(vb[i], -10.f), 10.f);
  }
}

// ---------------- launch ----------------
extern "C" void kernel_launch(void* const* d_in, const int* in_sizes, int n_in,
                              void* d_out, int out_size, void* d_ws, size_t ws_size,
                              hipStream_t stream){
  (void)in_sizes; (void)n_in; (void)out_size; (void)ws_size;
  const float* x          = (const float*)d_in[0];
  const float* payoffs    = (const float*)d_in[1];
  const int*   last_action= (const int*)d_in[2];
  const int*   step       = (const int*)d_in[3];
  const float* hiddens    = (const float*)d_in[4];
  const float* a_w1       = (const float*)d_in[5];
  const float* a_b1       = (const float*)d_in[6];
  const float* a_w2       = (const float*)d_in[7];
  const float* a_b2       = (const float*)d_in[8];
  const float* g_w1       = (const float*)d_in[9];
  const float* g_b1       = (const float*)d_in[10];
  const float* g_w2       = (const float*)d_in[11];
  const float* g_b2       = (const float*)d_in[12];
  const float* gru_wih    = (const float*)d_in[13];
  const float* gru_whh    = (const float*)d_in[14];
  const float* gru_bih    = (const float*)d_in[15];
  const float* gru_bhh    = (const float*)d_in[16];
  const float* head_w     = (const float*)d_in[17];
  const float* head_b     = (const float*)d_in[18];

  unsigned short* ws16 = (unsigned short*)d_ws;
  float* wsf = (float*)d_ws;
  float* outp = (float*)d_out;

  hipMemsetAsync((char*)d_ws + WS_ACC, 0, ACC_BYTES, stream);
  k_prep_w<<<1536, 256, 0, stream>>>(a_w1, g_w1, a_w2, g_w2, gru_wih, gru_whh, ws16);
  k_prep_b<<<1, 256, 0, stream>>>(x, a_w1, g_w1, a_b1, g_b1, a_b2, g_b2, wsf);
  k_pass1<<<2048, 512, 0, stream>>>(hiddens, payoffs, gru_wih, gru_bih, gru_bhh,
                                    ws16, wsf, wsf, outp);
  k_mid<<<1, 256, 0, stream>>>(wsf, wsf, head_w, head_b, step, outp);
  k_pass2<<<8192, 256, 0, stream>>>(outp, last_action, wsf, step);
}

// Round 6
// 711.811 us; speedup vs baseline: 1.0660x; 1.0660x over previous
//
#include <hip/hip_runtime.h>

// ---------------- problem constants ----------------
#define NCELLS 131072
#define HIDN 256
#define ODIM 128
#define FS 16384
#define DCC 4096
#define HALF_NOISE 16777216u   // (NCELLS*HIDN)/2

// ---------------- ws layout (bytes) ----------------
#define WS_WAG   0u          // 256x256 bf16 (a/g layer-1 h-part), [ch][k]
#define WS_W2C   131072u     // 128x256 bf16 ([a_w2 | -g_w2]), [ch][k]
#define WS_WIH   196608u     // 768x128 bf16 (gru_wih[:, :128]), [ch][k]
#define WS_WHH   393216u     // 768x256 bf16 (gru_whh), [ch][k]
#define WS_BAG   786432u     // 256 f32 folded layer-1 bias
#define WS_B2C   787456u     // 128 f32 (a_b2 - g_b2)
#define WS_ACC   788480u     // f32: fsum[2048] fsumdc[2048] combined[128] sumexp sumt
#define ACC_F     (WS_ACC/4)
#define ACC_BYTES 17152u
#define WS_FM    805632u     // 2048 f32
#define WS_GOP   813824u     // 256 f32
#define WS_GMEAN 814848u     // 256 f32

typedef __bf16 bf16x8 __attribute__((ext_vector_type(8)));
typedef float floatx4 __attribute__((ext_vector_type(4)));
#define MFMA16(a,b,c) __builtin_amdgcn_mfma_f32_16x16x32_bf16((a),(b),(c),0,0,0)

__device__ __forceinline__ unsigned short f2bf(float f){
  union { float f; unsigned int u; } v; v.f = f;
  unsigned int u = v.u;
  unsigned int r = (u + 0x7FFFu + ((u >> 16) & 1u)) >> 16;
  return (unsigned short)r;
}
__device__ __forceinline__ float bf2f(unsigned short s){
  union { unsigned int u; float f; } v; v.u = ((unsigned int)s) << 16; return v.f;
}
// fast transcendentals: v_exp_f32 + v_rcp_f32 (err < 1e-6, budget 1e-2)
__device__ __forceinline__ float sigm(float x){
  return __builtin_amdgcn_rcpf(1.0f + __expf(-x));
}
__device__ __forceinline__ float ftanh(float x){
  return 1.0f - 2.0f*__builtin_amdgcn_rcpf(1.0f + __expf(2.0f*x));
}

// swizzled LDS fragment load: element offset = row*width + (chunk ^ (row&7))*8
__device__ __forceinline__ bf16x8 ldfrag(const unsigned short* base, int row, int chunk, int width){
  return *(const bf16x8*)(base + row*width + (((chunk ^ (row & 7))) << 3));
}

// ---------------- threefry2x32, key = (0, 42) ----------------
__device__ __forceinline__ unsigned int rotl32(unsigned int x, int r){ return (x<<r)|(x>>(32-r)); }
__device__ __forceinline__ void threefry_0_42(unsigned int x0, unsigned int x1,
                                              unsigned int& o0, unsigned int& o1){
  const unsigned int k0 = 0u, k1 = 42u, k2 = 0x1BD11BDAu ^ 0u ^ 42u;
  x0 += k0; x1 += k1;
#define TFR(r) { x0 += x1; x1 = rotl32(x1,(r)); x1 ^= x0; }
  TFR(13) TFR(15) TFR(26) TFR(6)
  x0 += k1; x1 += k2 + 1u;
  TFR(17) TFR(29) TFR(16) TFR(24)
  x0 += k2; x1 += k0 + 2u;
  TFR(13) TFR(15) TFR(26) TFR(6)
  x0 += k0; x1 += k1 + 3u;
  TFR(17) TFR(29) TFR(16) TFR(24)
  x0 += k1; x1 += k2 + 4u;
  TFR(13) TFR(15) TFR(26) TFR(6)
  x0 += k2; x1 += k0 + 5u;
#undef TFR
  o0 = x0; o1 = x1;
}

// JAX partitionable-mode 32-bit random bits: full cipher of (idx>>32, idx) -> x0^x1
__device__ __forceinline__ unsigned int tf_bits_partitionable(unsigned int idx){
  unsigned int o0, o1;
  threefry_0_42(0u, idx, o0, o1);
  return o0 ^ o1;
}

__device__ __forceinline__ float giles_erfinv(float x){
  float w = -log1pf(-x*x);          // matches XLA ErfInv f32
  float p;
  if (w < 5.0f){
    w = w - 2.5f;
    p = 2.81022636e-08f;
    p = 3.43273939e-07f + p*w;
    p = -3.5233877e-06f + p*w;
    p = -4.39150654e-06f + p*w;
    p = 0.00021858087f  + p*w;
    p = -0.00125372503f + p*w;
    p = -0.00417768164f + p*w;
    p = 0.246640727f    + p*w;
    p = 1.50140941f     + p*w;
  } else {
    w = sqrtf(w) - 3.0f;
    p = -0.000200214257f;
    p = 0.000100950558f + p*w;
    p = 0.00134934322f  + p*w;
    p = -0.00367342844f + p*w;
    p = 0.00573950773f  + p*w;
    p = -0.0076224613f  + p*w;
    p = 0.00943887047f  + p*w;
    p = 1.00167406f     + p*w;
    p = 2.83297682f     + p*w;
  }
  return p*x;
}
__device__ __forceinline__ float bits_to_normal(unsigned int bits){
  union { unsigned int u; float f; } v; v.u = (bits >> 9) | 0x3f800000u;
  float f = v.f - 1.0f;                       // [0,1)
  const float lo = -0.99999994f;              // nextafter(-1,0)
  float u = fmaf(f, 2.0f, lo);                // matches jax uniform(lo, 1.0)
  u = fmaxf(u, lo);
  return 1.41421356237f * giles_erfinv(u);
}

// ---------------- prep: weight bf16 conversion + bias folds (merged) ----------------
__global__ void k_prep_w(const float* a_w1, const float* g_w1, const float* a_w2, const float* g_w2,
                         const float* gru_wih, const float* gru_whh, unsigned short* ws16,
                         const float* x, const float* a_b1, const float* g_b1,
                         const float* a_b2, const float* g_b2, float* wsf){
  if (blockIdx.x == 1536){
    int t = threadIdx.x;  // 256: fold x into layer-1 bias; combine layer-2 bias
    const float* wr = (t < 128) ? (a_w1 + t*384) : (g_w1 + (t-128)*384);
    float b = (t < 128) ? a_b1[t] : g_b1[t-128];
    const float4* wr4 = (const float4*)wr;
    const float4* x4  = (const float4*)x;
    float s = 0.f;
#pragma unroll 4
    for (int k = 0; k < 32; ++k){
      float4 w = wr4[k], xv = x4[k];
      s += w.x*xv.x + w.y*xv.y + w.z*xv.z + w.w*xv.w;
    }
    wsf[WS_BAG/4 + t] = b + s;
    if (t < 128) wsf[WS_B2C/4 + t] = a_b2[t] - g_b2[t];
    return;
  }
  int i = blockIdx.x*256 + threadIdx.x;
  if (i < 65536){                    // Wag
    int ch = i >> 8, k = i & 255;
    float v = (ch < 128) ? a_w1[ch*384 + 128 + k] : g_w1[(ch-128)*384 + 128 + k];
    ws16[WS_WAG/2 + i] = f2bf(v);
  } else if (i < 98304){             // W2c
    int j = i - 65536; int ch = j >> 8, k = j & 255;
    float v = (k < 128) ? a_w2[ch*128 + k] : -g_w2[ch*128 + (k-128)];
    ws16[WS_W2C/2 + j] = f2bf(v);
  } else if (i < 196608){            // Wih (k<128 part)
    int j = i - 98304; int ch = j >> 7, k = j & 127;
    ws16[WS_WIH/2 + j] = f2bf(gru_wih[ch*129 + k]);
  } else if (i < 393216){            // Whh
    int j = i - 196608; int ch = j >> 8, k = j & 255;
    ws16[WS_WHH/2 + j] = f2bf(gru_whh[ch*256 + k]);
  }
}

// ---------------- D-stage GEMM helpers (wave tile 64 rows x 32 ch) ----------------
__device__ __forceinline__ void gemm_gi(floatx4 acc[4][2], const unsigned short* Wih,
                                        const unsigned short* outlds, int cb, int lane, int rowoff){
  const int al = lane & 15, kg = lane >> 4;
#pragma unroll
  for (int kk = 0; kk < 4; ++kk){
    const int chunk = kk*4 + kg;
    bf16x8 a0 = ldfrag(outlds,      al, chunk, 128);
    bf16x8 a1 = ldfrag(outlds, 16 + al, chunk, 128);
    bf16x8 a2 = ldfrag(outlds, 32 + al, chunk, 128);
    bf16x8 a3 = ldfrag(outlds, 48 + al, chunk, 128);
    const int k = kk*32 + kg*8;
    bf16x8 b0 = *(const bf16x8*)(Wih + (rowoff + cb      + al)*128 + k);
    bf16x8 b1 = *(const bf16x8*)(Wih + (rowoff + cb + 16 + al)*128 + k);
    acc[0][0] = MFMA16(a0,b0,acc[0][0]); acc[1][0] = MFMA16(a1,b0,acc[1][0]);
    acc[2][0] = MFMA16(a2,b0,acc[2][0]); acc[3][0] = MFMA16(a3,b0,acc[3][0]);
    acc[0][1] = MFMA16(a0,b1,acc[0][1]); acc[1][1] = MFMA16(a1,b1,acc[1][1]);
    acc[2][1] = MFMA16(a2,b1,acc[2][1]); acc[3][1] = MFMA16(a3,b1,acc[3][1]);
  }
}
__device__ __forceinline__ void gemm_gh(floatx4 acc[4][2], const unsigned short* Whh,
                                        const unsigned short* hlds, int cb, int lane, int rowoff){
  const int al = lane & 15, kg = lane >> 4;
#pragma unroll
  for (int kk = 0; kk < 8; ++kk){
    const int chunk = kk*4 + kg;
    bf16x8 a0 = ldfrag(hlds,      al, chunk, 256);
    bf16x8 a1 = ldfrag(hlds, 16 + al, chunk, 256);
    bf16x8 a2 = ldfrag(hlds, 32 + al, chunk, 256);
    bf16x8 a3 = ldfrag(hlds, 48 + al, chunk, 256);
    const int k = kk*32 + kg*8;
    bf16x8 b0 = *(const bf16x8*)(Whh + (rowoff + cb      + al)*256 + k);
    bf16x8 b1 = *(const bf16x8*)(Whh + (rowoff + cb + 16 + al)*256 + k);
    acc[0][0] = MFMA16(a0,b0,acc[0][0]); acc[1][0] = MFMA16(a1,b0,acc[1][0]);
    acc[2][0] = MFMA16(a2,b0,acc[2][0]); acc[3][0] = MFMA16(a3,b0,acc[3][0]);
    acc[0][1] = MFMA16(a0,b1,acc[0][1]); acc[1][1] = MFMA16(a1,b1,acc[1][1]);
    acc[2][1] = MFMA16(a2,b1,acc[2][1]); acc[3][1] = MFMA16(a3,b1,acc[3][1]);
  }
}

// ---------------- pass 1: per-cell pipeline, 64 rows/block, 512 thr ----------------
__global__ __launch_bounds__(512, 2) void k_pass1(
    const float* __restrict__ hiddens, const float* __restrict__ payoffs,
    const float* __restrict__ gru_wih, const float* __restrict__ gru_bih,
    const float* __restrict__ gru_bhh,
    const unsigned short* __restrict__ ws16, const float* __restrict__ wsf,
    float* __restrict__ accf, float* __restrict__ d_out)
{
  __shared__ __align__(16) unsigned short h_lds[64*256];  // 32 KB
  __shared__ __align__(16) unsigned short u1[64*256];     // 32 KB: r1 -> out + scalars
  unsigned short* u2 = u1;                 // out 64x128 (first 8192 ushorts)
  float* tens = (float*)&u1[8192];         // 64 f32
  float* texp = tens + 64;                 // 64 f32
  float* pay  = tens + 128;                // 64 f32
  float* bsum = tens + 192;                // 256 f32

  const int tid = threadIdx.x;
  const int lane = tid & 63;
  const int wid  = tid >> 6;
  const int row0 = blockIdx.x * 64;
  const int al = lane & 15, kg = lane >> 4;
  const floatx4 vzero = {0.f, 0.f, 0.f, 0.f};

  // ---- stage h -> LDS (bf16, swizzled, packed b64 writes) ----
  {
    const float4* hg = (const float4*)(hiddens + (size_t)row0*256);
#pragma unroll
    for (int it = 0; it < 8; ++it){
      int i = it*512 + tid;            // 4096 float4 per tile
      float4 v = hg[i];
      int row = i >> 6;
      int ch  = (i & 63) << 2;
      int off = row*256 + (((ch >> 3) ^ (row & 7)) << 3) + (ch & 7);
      unsigned int p0 = (unsigned int)f2bf(v.x) | ((unsigned int)f2bf(v.y) << 16);
      unsigned int p1 = (unsigned int)f2bf(v.z) | ((unsigned int)f2bf(v.w) << 16);
      *(uint2*)(h_lds + off) = make_uint2(p0, p1);
    }
  }
  __syncthreads();

  // ---- stage A: [a1|g1] = relu(h @ Wag^T + bag) -> u1 ----
  {
    const unsigned short* Wag = ws16 + WS_WAG/2;
    const int mrow = (wid >> 2) * 32;
    const int ncol = (wid & 3) * 64;
    floatx4 acc[2][4];
#pragma unroll
    for (int m=0;m<2;m++)
#pragma unroll
      for (int n=0;n<4;n++) acc[m][n] = vzero;
#pragma unroll
    for (int kk = 0; kk < 8; ++kk){
      const int chunk = kk*4 + kg;
      bf16x8 a0 = ldfrag(h_lds, mrow      + al, chunk, 256);
      bf16x8 a1 = ldfrag(h_lds, mrow + 16 + al, chunk, 256);
      const int k = kk*32 + kg*8;
      bf16x8 b0 = *(const bf16x8*)(Wag + (ncol      + al)*256 + k);
      bf16x8 b1 = *(const bf16x8*)(Wag + (ncol + 16 + al)*256 + k);
      bf16x8 b2 = *(const bf16x8*)(Wag + (ncol + 32 + al)*256 + k);
      bf16x8 b3 = *(const bf16x8*)(Wag + (ncol + 48 + al)*256 + k);
      acc[0][0] = MFMA16(a0,b0,acc[0][0]); acc[1][0] = MFMA16(a1,b0,acc[1][0]);
      acc[0][1] = MFMA16(a0,b1,acc[0][1]); acc[1][1] = MFMA16(a1,b1,acc[1][1]);
      acc[0][2] = MFMA16(a0,b2,acc[0][2]); acc[1][2] = MFMA16(a1,b2,acc[1][2]);
      acc[0][3] = MFMA16(a0,b3,acc[0][3]); acc[1][3] = MFMA16(a1,b3,acc[1][3]);
    }
#pragma unroll
    for (int n=0;n<4;n++){
      int ch = ncol + n*16 + al;
      float bias = wsf[WS_BAG/4 + ch];
#pragma unroll
      for (int m=0;m<2;m++){
#pragma unroll
        for (int r=0;r<4;r++){
          int row = mrow + m*16 + kg*4 + r;
          float val = fmaxf(acc[m][n][r] + bias, 0.f);
          u1[row*256 + (((ch>>3) ^ (row&7))<<3) + (ch&7)] = f2bf(val);
        }
      }
    }
  }
  __syncthreads();

  // ---- stage B: out = r1 @ W2c^T + b2c ----
  floatx4 bacc[2][2];
  const int bmrow = (wid >> 2) * 32;
  const int bncol = (wid & 3) * 32;
  {
    const unsigned short* W2c = ws16 + WS_W2C/2;
#pragma unroll
    for (int m=0;m<2;m++)
#pragma unroll
      for (int n=0;n<2;n++) bacc[m][n] = vzero;
#pragma unroll
    for (int kk = 0; kk < 8; ++kk){
      const int chunk = kk*4 + kg;
      bf16x8 a0 = ldfrag(u1, bmrow      + al, chunk, 256);
      bf16x8 a1 = ldfrag(u1, bmrow + 16 + al, chunk, 256);
      const int k = kk*32 + kg*8;
      bf16x8 b0 = *(const bf16x8*)(W2c + (bncol      + al)*256 + k);
      bf16x8 b1 = *(const bf16x8*)(W2c + (bncol + 16 + al)*256 + k);
      bacc[0][0] = MFMA16(a0,b0,bacc[0][0]); bacc[1][0] = MFMA16(a1,b0,bacc[1][0]);
      bacc[0][1] = MFMA16(a0,b1,bacc[0][1]); bacc[1][1] = MFMA16(a1,b1,bacc[1][1]);
    }
  }
  __syncthreads();   // everyone done reading r1 -> reuse u1 for out

  // ---- u2 write + tension partials from registers (no u2 re-read, no conflicts) ----
  {
    float ts[2][4];
#pragma unroll
    for (int m=0;m<2;m++)
#pragma unroll
      for (int r=0;r<4;r++) ts[m][r] = 0.f;
#pragma unroll
    for (int n=0;n<2;n++){
      int ch = bncol + n*16 + al;
      float bias = wsf[WS_B2C/4 + ch];
#pragma unroll
      for (int m=0;m<2;m++){
#pragma unroll
        for (int r=0;r<4;r++){
          int row = bmrow + m*16 + kg*4 + r;
          float val = bacc[m][n][r] + bias;
          u2[row*128 + (((ch>>3) ^ (row&7))<<3) + (ch&7)] = f2bf(val);
          ts[m][r] += val*val;
        }
      }
    }
#pragma unroll
    for (int m=0;m<2;m++)
#pragma unroll
      for (int r=0;r<4;r++){
        float s = ts[m][r];
        s += __shfl_xor(s, 1);
        s += __shfl_xor(s, 2);
        s += __shfl_xor(s, 4);
        s += __shfl_xor(s, 8);
        if (al == 0) bsum[(bmrow + m*16 + kg*4 + r)*4 + (wid & 3)] = s;
      }
  }
  __syncthreads();
  if (tid < 64){
    float t = (bsum[tid*4] + bsum[tid*4+1] + bsum[tid*4+2] + bsum[tid*4+3]) * (1.0f/128.0f);
    tens[tid] = t;
    texp[tid] = __expf(t);
    pay[tid]  = payoffs[row0 + tid];
  }
  __syncthreads();

  // ---- softmax-mixture partials (waves 0-1 only; others fall through to GRU) ----
  if (tid < 128){
    int ch = tid;
    float s = 0.f;
    for (int row = 0; row < 64; ++row)
      s += texp[row] * bf2f(u2[row*128 + (((ch>>3) ^ (row&7))<<3) + (ch&7)]);
    atomicAdd(accf + ACC_F + 4096 + ch, s);
  } else if (tid == 128){
    float se = 0.f, st = 0.f;
    for (int r = 0; r < 64; ++r){ se += texp[r]; st += tens[r]; }
    atomicAdd(accf + ACC_F + 4224, se);
    atomicAdd(accf + ACC_F + 4225, st);
  }

  // ---- GRU: wave handles 64 rows x 32 channels (cb = wid*32) ----
  const unsigned short* Wih = ws16 + WS_WIH/2;
  const unsigned short* Whh = ws16 + WS_WHH/2;
  const int cb = wid * 32;

  float rr[4][2][4];
  {
    floatx4 acc[4][2];
#pragma unroll
    for (int m=0;m<4;m++){ acc[m][0] = vzero; acc[m][1] = vzero; }
    gemm_gi(acc, Wih, u2, cb, lane, 0);
    gemm_gh(acc, Whh, h_lds, cb, lane, 0);
#pragma unroll
    for (int n=0;n<2;n++){
      int ch = cb + n*16 + al;
      float bb = gru_bih[ch] + gru_bhh[ch];
      float wt = gru_wih[ch*129 + 128];
#pragma unroll
      for (int m=0;m<4;m++)
#pragma unroll
        for (int r=0;r<4;r++){
          int row = m*16 + kg*4 + r;
          rr[m][n][r] = sigm(acc[m][n][r] + bb + tens[row]*wt);
        }
    }
  }

  float nnv[4][2][4];
  {
    floatx4 gin[4][2], ghn[4][2];
#pragma unroll
    for (int m=0;m<4;m++){ gin[m][0]=vzero; gin[m][1]=vzero; ghn[m][0]=vzero; ghn[m][1]=vzero; }
    gemm_gi(gin, Wih, u2, cb, lane, 512);
    gemm_gh(ghn, Whh, h_lds, cb, lane, 512);
#pragma unroll
    for (int n=0;n<2;n++){
      int ch = cb + n*16 + al;
      float bi = gru_bih[512+ch];
      float bh = gru_bhh[512+ch];
      float wt = gru_wih[(512+ch)*129 + 128];
#pragma unroll
      for (int m=0;m<4;m++)
#pragma unroll
        for (int r=0;r<4;r++){
          int row = m*16 + kg*4 + r;
          nnv[m][n][r] = ftanh(gin[m][n][r] + bi + tens[row]*wt + rr[m][n][r]*(ghn[m][n][r] + bh));
        }
    }
  }

  {
    floatx4 acc[4][2];
#pragma unroll
    for (int m=0;m<4;m++){ acc[m][0] = vzero; acc[m][1] = vzero; }
    gemm_gi(acc, Wih, u2, cb, lane, 256);
    gemm_gh(acc, Whh, h_lds, cb, lane, 256);
    float cs[2] = {0.f, 0.f};
#pragma unroll
    for (int n=0;n<2;n++){
      int ch = cb + n*16 + al;
      float bb = gru_bih[256+ch] + gru_bhh[256+ch];
      float wt = gru_wih[(256+ch)*129 + 128];
#pragma unroll
      for (int m=0;m<4;m++)
#pragma unroll
        for (int r=0;r<4;r++){
          int row = m*16 + kg*4 + r;
          float z = sigm(acc[m][n][r] + bb + tens[row]*wt);
          float h = bf2f(h_lds[row*256 + (((ch>>3) ^ (row&7))<<3) + (ch&7)]);
          float nh = (1.0f - z)*nnv[m][n][r] + z*h;
          nh *= (0.9f + 0.02f*pay[row]);
          nh = fminf(fmaxf(nh, -10.0f), 10.0f);
          d_out[129 + (size_t)(row0 + row)*256 + ch] = nh;
          cs[n] += nh;
        }
    }
#pragma unroll
    for (int n=0;n<2;n++){
      float c = cs[n];
      c += __shfl_xor(c, 16);
      c += __shfl_xor(c, 32);
      if (lane < 16) bsum[cb + n*16 + lane] = c;
    }
  }
  __syncthreads();

  if (tid < 256){
    int f = row0 >> 14;
    atomicAdd(accf + ACC_F + f*256 + tid, bsum[tid]);
    if ((row0 & (FS-1)) < DCC)
      atomicAdd(accf + ACC_F + 2048 + f*256 + tid, bsum[tid]);
  }
}

// ---------------- mid: faction stats + head ----------------
__global__ void k_mid(const float* __restrict__ accf, float* __restrict__ wsf,
                      const float* __restrict__ head_w, const float* __restrict__ head_b,
                      const int* __restrict__ stepp, float* __restrict__ d_out){
  int t = threadIdx.x;  // 256
  const float* fsum   = accf + ACC_F;
  const float* fsumdc = fsum + 2048;
  const float* comb   = fsum + 4096;
  int step = *stepp;

  float g = 0.f;
  for (int f = 0; f < 8; ++f) g += fsum[f*256 + t];
  float gop = g * (1.0f/131072.0f);
  wsf[WS_GOP/4 + t] = gop;

  float tot = 0.f;
  for (int f = 0; f < 8; ++f){
    float s1  = fsum[f*256 + t];
    float fmv = s1 * (1.0f/16384.0f);
    wsf[WS_FM/4 + f*256 + t] = fmv;
    float sh2 = s1;
    if (step > 5){
      float sdc = 0.85f*fsumdc[f*256 + t] + 0.15f*4096.0f*fmv;
      sh2 = s1 + 0.15f*(4096.0f*gop - sdc);
    }
    tot += sh2;
  }
  wsf[WS_GMEAN/4 + t] = tot * (1.0f/131072.0f);

  if (t < 128){
    float inv = 1.0f / fsum[4224];
    const float4* hw = (const float4*)(head_w + t*128);
    const float4* cb4 = (const float4*)comb;
    float p = 0.f;
    for (int c = 0; c < 32; ++c){
      float4 w = hw[c], cc = cb4[c];
      p += w.x*cc.x + w.y*cc.y + w.z*cc.z + w.w*cc.w;
    }
    d_out[t] = head_b[t] + p*inv;
  }
  if (t == 0) d_out[128] = fsum[4225] * (1.0f/131072.0f);
}

// ---------------- pass 2: sync/debate/coop/noise, in place in d_out ----------------
__global__ __launch_bounds__(256) void k_pass2(float* __restrict__ dout,
                                               const int* __restrict__ last_action,
                                               const float* __restrict__ wsf,
                                               const int* __restrict__ stepp){
  const int t = threadIdx.x;
  const int rA = blockIdx.x*8 + (t >> 5);
  const int rB = rA + 65536;
  const int ch0 = (t & 31) * 8;
  const int step = *stepp;
  const float* fm    = wsf + WS_FM/4;
  const float* gop   = wsf + WS_GOP/4;
  const float* gmean = wsf + WS_GMEAN/4;
  const int coopA = last_action[rA];
  const int coopB = last_action[rB];
  const bool debA = (step > 5) && ((rA & (FS-1)) < DCC);
  const bool debB = (step > 5) && ((rB & (FS-1)) < DCC);
  const int fA = rA >> 14, fB = rB >> 14;
  float* pa = dout + 129 + (size_t)rA*256 + ch0;
  float* pb = dout + 129 + (size_t)rB*256 + ch0;

  float va[8], vb[8];
#pragma unroll
  for (int i=0;i<8;i++){ va[i] = pa[i]; vb[i] = pb[i]; }
#pragma unroll
  for (int i=0;i<8;i++){
    int ch = ch0 + i;
    float p = 0.85f*va[i] + 0.15f*fm[fA*256 + ch];
    if (debA) p = 0.85f*p + 0.15f*gop[ch];
    if (coopA) p += 0.05f*(gmean[ch] - p);
    va[i] = p;
    float q = 0.85f*vb[i] + 0.15f*fm[fB*256 + ch];
    if (debB) q = 0.85f*q + 0.15f*gop[ch];
    if (coopB) q += 0.05f*(gmean[ch] - q);
    vb[i] = q;
  }
  // JAX partitionable threefry noise: bits(idx) = x0^x1 of cipher(0, idx)
  if (!coopA){
    const unsigned baseA = (unsigned)rA*256u + (unsigned)ch0;
#pragma unroll
    for (int i=0;i<8;i++)
      va[i] += 0.02f*bits_to_normal(tf_bits_partitionable(baseA + i));
  }
  if (!coopB){
    const unsigned baseB = (unsigned)rA*256u + (unsigned)ch0 + HALF_NOISE;
#pragma unroll
    for (int i=0;i<8;i++)
      vb[i] += 0.02f*bits_to_normal(tf_bits_partitionable(baseB + i));
  }
#pragma unroll
  for (int i=0;i<8;i++){
    pa[i] = fminf(fmaxf(va[i], -10.f), 10.f);
    pb[i] = fminf(fmaxf(vb[i], -10.f), 10.f);
  }
}

// ---------------- launch ----------------
extern "C" void kernel_launch(void* const* d_in, const int* in_sizes, int n_in,
                              void* d_out, int out_size, void* d_ws, size_t ws_size,
                              hipStream_t stream){
  (void)in_sizes; (void)n_in; (void)out_size; (void)ws_size;
  const float* x          = (const float*)d_in[0];
  const float* payoffs    = (const float*)d_in[1];
  const int*   last_action= (const int*)d_in[2];
  const int*   step       = (const int*)d_in[3];
  const float* hiddens    = (const float*)d_in[4];
  const float* a_w1       = (const float*)d_in[5];
  const float* a_b1       = (const float*)d_in[6];
  const float* a_w2       = (const float*)d_in[7];
  const float* a_b2       = (const float*)d_in[8];
  const float* g_w1       = (const float*)d_in[9];
  const float* g_b1       = (const float*)d_in[10];
  const float* g_w2       = (const float*)d_in[11];
  const float* g_b2       = (const float*)d_in[12];
  const float* gru_wih    = (const float*)d_in[13];
  const float* gru_whh    = (const float*)d_in[14];
  const float* gru_bih    = (const float*)d_in[15];
  const float* gru_bhh    = (const float*)d_in[16];
  const float* head_w     = (const float*)d_in[17];
  const float* head_b     = (const float*)d_in[18];

  unsigned short* ws16 = (unsigned short*)d_ws;
  float* wsf = (float*)d_ws;
  float* outp = (float*)d_out;

  hipMemsetAsync((char*)d_ws + WS_ACC, 0, ACC_BYTES, stream);
  k_prep_w<<<1537, 256, 0, stream>>>(a_w1, g_w1, a_w2, g_w2, gru_wih, gru_whh, ws16,
                                     x, a_b1, g_b1, a_b2, g_b2, wsf);
  k_pass1<<<2048, 512, 0, stream>>>(hiddens, payoffs, gru_wih, gru_bih, gru_bhh,
                                    ws16, wsf, wsf, outp);
  k_mid<<<1, 256, 0, stream>>>(wsf, wsf, head_w, head_b, step, outp);
  k_pass2<<<8192, 256, 0, stream>>>(outp, last_action, wsf, step);
}